// Round 1
// baseline (190.569 us; speedup 1.0000x reference)
//
#include <hip/hip_runtime.h>
#include <stdint.h>
#include <math.h>

#define B_ 4
#define T_ 4096
#define C_ 1024
#define H_ 128

typedef __attribute__((ext_vector_type(8))) short s16x8;   // 8 bf16 (4 VGPRs)
typedef __attribute__((ext_vector_type(4))) float f32x4;   // MFMA accumulator

__device__ __forceinline__ unsigned short f2bf(float f) {
    union { float f; unsigned u; } v; v.f = f;
    unsigned r = v.u + 0x7fffu + ((v.u >> 16) & 1u);
    return (unsigned short)(r >> 16);
}

__device__ __forceinline__ s16x8 as_frag(uint4 u) {
    union { uint4 u; s16x8 s; } v; v.u = u; return v.s;
}

// number of work-chunks per batch for chunk size CH (64 key-tiles max)
__host__ __device__ constexpr int chunks_total(int CH) {
    int a = 64 / CH, b = 64 % CH;
    return CH * a * (a + 1) / 2 + b * (a + 1);
}

// softmax scale folded into Q at projection time: 1/sqrt(128) * log2(e)
#define QSC (0.0883883476f * 1.4426950408f)

// ---------------------------------------------------------------------------
// Kernel 1: W [1024][128] fp32 -> Wt [3*128][1024] bf16 (transposed, converted)
// ---------------------------------------------------------------------------
__global__ __launch_bounds__(256) void k_wt(const float* __restrict__ Wk,
                                            const float* __restrict__ Wq,
                                            const float* __restrict__ Wv,
                                            unsigned short* __restrict__ Wt) {
    __shared__ float tile[64][65];
    int w = blockIdx.z;  // 0=K, 1=Q, 2=V
    const float* W = (w == 0) ? Wk : (w == 1) ? Wq : Wv;
    int c0 = blockIdx.x * 64, h0 = blockIdx.y * 64;
    int tid = threadIdx.x;
#pragma unroll
    for (int k = 0; k < 16; k++) {
        int idx = tid + k * 256;
        int r = idx >> 6, c = idx & 63;
        tile[r][c] = W[(size_t)(c0 + r) * H_ + h0 + c];
    }
    __syncthreads();
#pragma unroll
    for (int k = 0; k < 16; k++) {
        int idx = tid + k * 256;
        int hh = idx >> 6, cc = idx & 63;
        Wt[(size_t)(w * H_ + h0 + hh) * C_ + c0 + cc] = f2bf(tile[cc][hh]);
    }
}

// ---------------------------------------------------------------------------
// Kernel 2: fused QKV GEMM. v2: 32-row x 384-col tiles, 512 threads (8 waves),
// grid 512 -> 2 blocks/CU = 16 waves/CU (was 8), x read ONCE (was twice),
// 2-deep HBM prefetch (manually 2x-unrolled so register names stay static).
// V is written t-PERMUTED within each 32-block (consumed by k_attn PV order).
// ---------------------------------------------------------------------------
__global__ __launch_bounds__(512, 4) void k_qkv(const float* __restrict__ x,
                                                const unsigned short* __restrict__ Wt,
                                                unsigned short* __restrict__ Qb,
                                                unsigned short* __restrict__ Kb,
                                                unsigned short* __restrict__ Vt) {
    __shared__ unsigned short a_lds[2][32 * 72];  // 2 x 4608 B
    int tid = threadIdx.x;
    int wv = tid >> 6, lane = tid & 63, quad = lane >> 4, lo = lane & 15;
    int r0 = blockIdx.x * 32;

    f32x4 acc[3][2];
#pragma unroll
    for (int i = 0; i < 3; i++)
#pragma unroll
        for (int j = 0; j < 2; j++) acc[i][j] = (f32x4){0.f, 0.f, 0.f, 0.f};

    const int row_s = tid >> 4;          // [0,32)
    const int seg_s = (tid & 15) * 4;    // [0,64) step 4
    size_t xbase = (size_t)(r0 + row_s) * C_ + seg_s;

    const unsigned short* wp[3];
#pragma unroll
    for (int nt = 0; nt < 3; nt++)
        wp[nt] = Wt + (size_t)((wv * 3 + nt) * 16 + lo) * C_ + quad * 8;

    auto load_x = [&](int kc) -> float4 {
        return *(const float4*)(x + xbase + kc * 64);
    };
    auto pack_store = [&](unsigned short* buf, float4 f) {
        uint2 u;
        u.x = (unsigned)f2bf(f.x) | ((unsigned)f2bf(f.y) << 16);
        u.y = (unsigned)f2bf(f.z) | ((unsigned)f2bf(f.w) << 16);
        *(uint2*)&buf[row_s * 72 + seg_s] = u;
    };
    auto compute = [&](const unsigned short* buf, int kc) {
        s16x8 b[3][2];
#pragma unroll
        for (int nt = 0; nt < 3; nt++)
#pragma unroll
            for (int kh = 0; kh < 2; kh++)
                b[nt][kh] = *(const s16x8*)(wp[nt] + kc * 64 + kh * 32);
        s16x8 af[2][2];
#pragma unroll
        for (int mt = 0; mt < 2; mt++)
#pragma unroll
            for (int kh = 0; kh < 2; kh++)
                af[mt][kh] = *(const s16x8*)&buf[(mt * 16 + lo) * 72 + kh * 32 + quad * 8];
#pragma unroll
        for (int nt = 0; nt < 3; nt++)
#pragma unroll
            for (int kh = 0; kh < 2; kh++)
#pragma unroll
                for (int mt = 0; mt < 2; mt++)
                    acc[nt][mt] = __builtin_amdgcn_mfma_f32_16x16x32_bf16(
                        af[mt][kh], b[nt][kh], acc[nt][mt], 0, 0, 0);
    };

    float4 p0 = load_x(0);
    float4 p1 = load_x(1);
    pack_store(a_lds[0], p0);
    __syncthreads();

    for (int kc2 = 0; kc2 < 8; kc2++) {
        int kc = kc2 * 2;
        if (kc + 2 < 16) p0 = load_x(kc + 2);   // 2-deep prefetch
        compute(a_lds[0], kc);
        pack_store(a_lds[1], p1);               // p1 issued 2 barriers ago
        __syncthreads();
        if (kc + 3 < 16) p1 = load_x(kc + 3);
        compute(a_lds[1], kc + 1);
        if (kc + 2 < 16) pack_store(a_lds[0], p0);
        __syncthreads();
    }

    // Epilogue. C-layout: row = mt*16 + quad*4 + r, col = (wv*3+nt)*16 + lo
#pragma unroll
    for (int nt = 0; nt < 3; nt++) {
        int col = (wv * 3 + nt) * 16 + lo;
        int w = col >> 7, h = col & 127;
#pragma unroll
        for (int mt = 0; mt < 2; mt++) {
            int mrow = r0 + mt * 16 + quad * 4;
            if (w == 2) {
                int b = mrow >> 12, t0 = mrow & 4095;
                // permuted t within 32-block (see k_attn PV fragment order)
                int tp = (t0 & ~31) + (((t0 & 15) >> 2) << 3) + (((t0 >> 4) & 1) << 2);
                uint2 pk;
                pk.x = (unsigned)f2bf(acc[nt][mt][0]) | ((unsigned)f2bf(acc[nt][mt][1]) << 16);
                pk.y = (unsigned)f2bf(acc[nt][mt][2]) | ((unsigned)f2bf(acc[nt][mt][3]) << 16);
                *(uint2*)(Vt + (size_t)(b * H_ + h) * T_ + tp) = pk;
            } else if (w == 1) {
                unsigned short* dst = Qb + (size_t)mrow * H_ + h;
#pragma unroll
                for (int r = 0; r < 4; r++)
                    dst[(size_t)r * H_] = f2bf(acc[nt][mt][r] * QSC);
            } else {
                unsigned short* dst = Kb + (size_t)mrow * H_ + h;
#pragma unroll
                for (int r = 0; r < 4; r++)
                    dst[(size_t)r * H_] = f2bf(acc[nt][mt][r]);
            }
        }
    }
}

// ---------------------------------------------------------------------------
// Kernel 3: causal flash attention, S^T formulation. v2 changes:
//  - EQUAL-WORK chunking: each block owns <=CH contiguous key-tiles of one
//    q-tile (nc(qt)=ceil((qt+1)/CH)); all 4*NCH blocks co-resident -> no
//    dispatch tail (fixes the 22% time-avg occupancy = load imbalance).
//  - T13 defer-max (THR=8): row-max shuffles + O-rescale only when
//    __any(lane_max > m_i + 8); common path has NO cross-lane ops.
//  - l_i kept as per-lane partial; cross-quad sum once after the loop.
// CH == 0: direct (no workspace) fallback, full row range per block.
// ---------------------------------------------------------------------------
#define LOAD_KV(kv0)                                                            \
    do {                                                                        \
        const uint4* kg = (const uint4*)(Kb + (size_t)(batch * T_ + (kv0) + srow_k) * H_); \
        pk0 = kg[sseg_k + 0]; pk1 = kg[sseg_k + 1];                             \
        pk2 = kg[sseg_k + 2]; pk3 = kg[sseg_k + 3];                             \
        const uint4* vg = (const uint4*)(Vt + (size_t)(batch * H_ + srow_v) * T_ + (kv0)); \
        pv0 = vg[sseg_v + 0]; pv1 = vg[sseg_v + 1];                             \
        pv2 = vg[sseg_v + 2]; pv3 = vg[sseg_v + 3];                             \
    } while (0)

template <int CH>
__global__ __launch_bounds__(256, 3) void k_attn(const unsigned short* __restrict__ Qb,
                                                 const unsigned short* __restrict__ Kb,
                                                 const unsigned short* __restrict__ Vt,
                                                 float* __restrict__ Opart,
                                                 float* __restrict__ Mpart,
                                                 float* __restrict__ Lpart,
                                                 float* __restrict__ out) {
    __shared__ uint4 kbuf[64 * 16];   // 16 KB
    __shared__ uint4 vbuf[128 * 8];   // 16 KB (t-permuted V^T rows)

    int tid = threadIdx.x;
    int wv = tid >> 6, lane = tid & 63, quad = lane >> 4, lo = lane & 15;

    int id = blockIdx.x;
    int qt, batch, tbeg, tend, slot = 0;
    if constexpr (CH > 0) {
        slot = id >> 2; batch = id & 3;       // slot ascending <=> qt descending
        int s = slot, q = 63;
        for (;;) { int nc = (q + CH) / CH; if (s < nc) break; s -= nc; --q; }
        qt = q;
        tbeg = s * CH;
        tend = min(tbeg + CH, qt + 1);
    } else {
        qt = 63 - (id >> 2); batch = id & 3;
        tbeg = 0; tend = qt + 1;
    }
    int m0 = qt * 64 + wv * 16;
    int query = m0 + lo;

    s16x8 qf[4];
    size_t qrow = (size_t)(batch * T_ + m0 + lo) * H_;
#pragma unroll
    for (int ks = 0; ks < 4; ks++)
        qf[ks] = *(const s16x8*)(Qb + qrow + ks * 32 + quad * 8);

    f32x4 acc_o[8];   // O[query=lo][d = o*16 + quad*4 + r]
#pragma unroll
    for (int o = 0; o < 8; o++) acc_o[o] = (f32x4){0.f, 0.f, 0.f, 0.f};
    float m_i = -INFINITY, l_i = 0.f;   // l_i: per-lane PARTIAL (quad slice)

    const int srow_k = tid >> 2, sseg_k = (tid & 3) * 4;
    const int srow_v = tid >> 1, sseg_v = (tid & 1) * 4;

    uint4 pk0, pk1, pk2, pk3, pv0, pv1, pv2, pv3;
    LOAD_KV(tbeg * 64);

    for (int t = tbeg; t < tend; ++t) {
        int kv0 = t * 64;
        kbuf[srow_k * 16 + ((sseg_k + 0) ^ (srow_k & 15))] = pk0;
        kbuf[srow_k * 16 + ((sseg_k + 1) ^ (srow_k & 15))] = pk1;
        kbuf[srow_k * 16 + ((sseg_k + 2) ^ (srow_k & 15))] = pk2;
        kbuf[srow_k * 16 + ((sseg_k + 3) ^ (srow_k & 15))] = pk3;
        vbuf[srow_v * 8 + ((sseg_v + 0) ^ (srow_v & 7))] = pv0;
        vbuf[srow_v * 8 + ((sseg_v + 1) ^ (srow_v & 7))] = pv1;
        vbuf[srow_v * 8 + ((sseg_v + 2) ^ (srow_v & 7))] = pv2;
        vbuf[srow_v * 8 + ((sseg_v + 3) ^ (srow_v & 7))] = pv3;
        __syncthreads();
        if (t + 1 < tend) LOAD_KV((t + 1) * 64);

        // S^T = K Q^T: lane holds S[query=lo][key = kv0 + nt*16 + quad*4 + r]
        f32x4 s_acc[4];
#pragma unroll
        for (int nt = 0; nt < 4; nt++) s_acc[nt] = (f32x4){0.f, 0.f, 0.f, 0.f};
#pragma unroll
        for (int ks = 0; ks < 4; ks++) {
#pragma unroll
            for (int nt = 0; nt < 4; nt++) {
                s16x8 kf = as_frag(kbuf[(nt * 16 + lo) * 16 + ((ks * 4 + quad) ^ lo)]);
                s_acc[nt] = __builtin_amdgcn_mfma_f32_16x16x32_bf16(kf, qf[ks], s_acc[nt], 0, 0, 0);
            }
        }

        float p[4][4];
        bool diag = (t == qt);
#pragma unroll
        for (int nt = 0; nt < 4; nt++)
#pragma unroll
            for (int r = 0; r < 4; r++) {
                float sv = s_acc[nt][r];
                if (diag && (kv0 + nt * 16 + quad * 4 + r > query)) sv = -INFINITY;
                p[nt][r] = sv;
            }

        // per-lane max only; cross-lane work deferred (T13, THR=8)
        float mx = p[0][0];
#pragma unroll
        for (int nt = 0; nt < 4; nt++)
#pragma unroll
            for (int r = 0; r < 4; r++) mx = fmaxf(mx, p[nt][r]);
        if (__any(mx > m_i + 8.0f)) {
            float rm = fmaxf(mx, __shfl_xor(mx, 16));
            rm = fmaxf(rm, __shfl_xor(rm, 32));
            float mnew = fmaxf(m_i, rm);
            float alpha = exp2f(m_i - mnew);
            l_i *= alpha;
            m_i = mnew;
#pragma unroll
            for (int o = 0; o < 8; o++)
#pragma unroll
                for (int r = 0; r < 4; r++) acc_o[o][r] *= alpha;
        }
        float rs = 0.f;
#pragma unroll
        for (int nt = 0; nt < 4; nt++)
#pragma unroll
            for (int r = 0; r < 4; r++) {
                float pv = exp2f(p[nt][r] - m_i);   // bounded by 2^8
                p[nt][r] = pv;
                rs += pv;
            }
        l_i += rs;   // per-lane partial; summed across quads after loop

        // pack P straight into B-fragments (truncation; P in [0, 256])
        s16x8 pf[2];
#pragma unroll
        for (int kt = 0; kt < 2; kt++) {
            uint4 u;
            u.x = (__float_as_uint(p[2 * kt][0]) >> 16) | ((__float_as_uint(p[2 * kt][1]) >> 16) << 16);
            u.y = (__float_as_uint(p[2 * kt][2]) >> 16) | ((__float_as_uint(p[2 * kt][3]) >> 16) << 16);
            u.z = (__float_as_uint(p[2 * kt + 1][0]) >> 16) | ((__float_as_uint(p[2 * kt + 1][1]) >> 16) << 16);
            u.w = (__float_as_uint(p[2 * kt + 1][2]) >> 16) | ((__float_as_uint(p[2 * kt + 1][3]) >> 16) << 16);
            pf[kt] = as_frag(u);
        }

        // O^T += V^T P^T  (A = vf from permuted vbuf, B = pf)
#pragma unroll
        for (int kt = 0; kt < 2; kt++)
#pragma unroll
            for (int o = 0; o < 8; o++) {
                int vrow = o * 16 + lo;
                s16x8 vf = as_frag(vbuf[vrow * 8 + ((kt * 4 + quad) ^ (vrow & 7))]);
                acc_o[o] = __builtin_amdgcn_mfma_f32_16x16x32_bf16(vf, pf[kt], acc_o[o], 0, 0, 0);
            }
        __syncthreads();
    }

    l_i += __shfl_xor(l_i, 16);
    l_i += __shfl_xor(l_i, 32);

    if constexpr (CH > 0) {
        constexpr int NCH = chunks_total(CH);
        size_t pr = (size_t)(batch * NCH + slot) * 64 + wv * 16 + lo;
        float* Op = Opart + pr * 128;
#pragma unroll
        for (int o = 0; o < 8; o++) {
            float4 v = {acc_o[o][0], acc_o[o][1], acc_o[o][2], acc_o[o][3]};
            *(float4*)(Op + o * 16 + quad * 4) = v;
        }
        if (quad == 0) { Mpart[pr] = m_i; Lpart[pr] = l_i; }
    } else {
        float inv = 1.0f / l_i;
        int rowg = batch * T_ + m0 + lo;
#pragma unroll
        for (int o = 0; o < 8; o++) {
            float4 v = {acc_o[o][0] * inv, acc_o[o][1] * inv,
                        acc_o[o][2] * inv, acc_o[o][3] * inv};
            *(float4*)(out + (size_t)rowg * H_ + o * 16 + quad * 4) = v;
        }
    }
}

// ---------------------------------------------------------------------------
// Kernel 4: combine variable-count partials, online flash-rescale (no arrays
// -> no scratch). Slot base for qt via closed form of S(n) = sum ceil(k/CH).
// ---------------------------------------------------------------------------
template <int CH>
__global__ __launch_bounds__(256) void k_comb(const float* __restrict__ Opart,
                                              const float* __restrict__ Mpart,
                                              const float* __restrict__ Lpart,
                                              float* __restrict__ out) {
    constexpr int NCH = chunks_total(CH);
    int tid = threadIdx.x;
    int row = blockIdx.x * 8 + (tid >> 5);
    int h4 = (tid & 31) * 4;
    int batch = row >> 12, t = row & 4095, qt = t >> 6;
    int n = qt + 1;
    int nc = (qt + CH) / CH;
    int a = n / CH, b = n % CH;
    int S = CH * a * (a + 1) / 2 + b * (a + 1);
    int base = NCH - S;
    float M = -INFINITY, den = 0.f;
    float4 o = {0.f, 0.f, 0.f, 0.f};
    for (int s = 0; s < nc; ++s) {
        size_t pr = (size_t)(batch * NCH + base + s) * 64 + (t & 63);
        float ms = Mpart[pr], ls = Lpart[pr];
        float4 v = *(const float4*)(Opart + pr * 128 + h4);
        float Mn = fmaxf(M, ms);
        float wa = exp2f(M - Mn), wb = exp2f(ms - Mn);
        den = den * wa + ls * wb;
        o.x = o.x * wa + v.x * wb;
        o.y = o.y * wa + v.y * wb;
        o.z = o.z * wa + v.z * wb;
        o.w = o.w * wa + v.w * wb;
        M = Mn;
    }
    float inv = 1.0f / den;
    float4 r = {o.x * inv, o.y * inv, o.z * inv, o.w * inv};
    *(float4*)(out + (size_t)row * H_ + h4) = r;
}

// ---------------------------------------------------------------------------
extern "C" void kernel_launch(void* const* d_in, const int* in_sizes, int n_in,
                              void* d_out, int out_size, void* d_ws, size_t ws_size,
                              hipStream_t stream) {
    const float* x  = (const float*)d_in[0];
    const float* Wk = (const float*)d_in[1];
    const float* Wq = (const float*)d_in[2];
    const float* Wv = (const float*)d_in[3];
    char* ws = (char*)d_ws;
    unsigned short* Wt = (unsigned short*)ws;                 // 768 KB
    unsigned short* Qb = (unsigned short*)(ws + (1u << 20));  // 4 MB
    unsigned short* Kb = (unsigned short*)(ws + (5u << 20));  // 4 MB
    unsigned short* Vt = (unsigned short*)(ws + (9u << 20));  // 4 MB -> end 13 MB
    float* out = (float*)d_out;

    const size_t base = (size_t)13 << 20;
    constexpr int NCH10 = chunks_total(10);  // 238 chunks/batch
    constexpr int NCH21 = chunks_total(21);  // 130 chunks/batch (smaller ws)
    auto need_for = [&](int nch) {
        return base + (size_t)4 * nch * 64 * (128 * 4) + 2 * (size_t)4 * nch * 64 * 4;
    };

    k_wt  <<<dim3(16, 2, 3), 256, 0, stream>>>(Wk, Wq, Wv, Wt);
    k_qkv <<<dim3(512), 512, 0, stream>>>(x, Wt, Qb, Kb, Vt);

    if (ws_size >= need_for(NCH10)) {
        float* Op = (float*)(ws + base);
        float* Mp = Op + (size_t)4 * NCH10 * 64 * 128;
        float* Lp = Mp + (size_t)4 * NCH10 * 64;
        k_attn<10><<<4 * NCH10, 256, 0, stream>>>(Qb, Kb, Vt, Op, Mp, Lp, out);
        k_comb<10><<<2048, 256, 0, stream>>>(Op, Mp, Lp, out);
    } else if (ws_size >= need_for(NCH21)) {
        float* Op = (float*)(ws + base);
        float* Mp = Op + (size_t)4 * NCH21 * 64 * 128;
        float* Lp = Mp + (size_t)4 * NCH21 * 64;
        k_attn<21><<<4 * NCH21, 256, 0, stream>>>(Qb, Kb, Vt, Op, Mp, Lp, out);
        k_comb<21><<<2048, 256, 0, stream>>>(Op, Mp, Lp, out);
    } else {
        k_attn<0><<<256, 256, 0, stream>>>(Qb, Kb, Vt, nullptr, nullptr, nullptr, out);
    }
}

// Round 2
// 174.647 us; speedup vs baseline: 1.0912x; 1.0912x over previous
//
#include <hip/hip_runtime.h>
#include <stdint.h>
#include <math.h>

#define B_ 4
#define T_ 4096
#define C_ 1024
#define H_ 128

typedef __attribute__((ext_vector_type(8))) short s16x8;   // 8 bf16 (4 VGPRs)
typedef __attribute__((ext_vector_type(4))) float f32x4;   // MFMA accumulator

__device__ __forceinline__ unsigned short f2bf(float f) {
    union { float f; unsigned u; } v; v.f = f;
    unsigned r = v.u + 0x7fffu + ((v.u >> 16) & 1u);
    return (unsigned short)(r >> 16);
}

__device__ __forceinline__ s16x8 as_frag(uint4 u) {
    union { uint4 u; s16x8 s; } v; v.u = u; return v.s;
}

// number of work-chunks per batch for chunk size CH (64 key-tiles max)
__host__ __device__ constexpr int chunks_total(int CH) {
    int a = 64 / CH, b = 64 % CH;
    return CH * a * (a + 1) / 2 + b * (a + 1);
}

// softmax scale folded into Q at projection time: 1/sqrt(128) * log2(e)
#define QSC (0.0883883476f * 1.4426950408f)

// ---------------------------------------------------------------------------
// Kernel 1: W [1024][128] fp32 -> Wt [3*128][1024] bf16 (transposed, converted)
// ---------------------------------------------------------------------------
__global__ __launch_bounds__(256) void k_wt(const float* __restrict__ Wk,
                                            const float* __restrict__ Wq,
                                            const float* __restrict__ Wv,
                                            unsigned short* __restrict__ Wt) {
    __shared__ float tile[64][65];
    int w = blockIdx.z;  // 0=K, 1=Q, 2=V
    const float* W = (w == 0) ? Wk : (w == 1) ? Wq : Wv;
    int c0 = blockIdx.x * 64, h0 = blockIdx.y * 64;
    int tid = threadIdx.x;
#pragma unroll
    for (int k = 0; k < 16; k++) {
        int idx = tid + k * 256;
        int r = idx >> 6, c = idx & 63;
        tile[r][c] = W[(size_t)(c0 + r) * H_ + h0 + c];
    }
    __syncthreads();
#pragma unroll
    for (int k = 0; k < 16; k++) {
        int idx = tid + k * 256;
        int hh = idx >> 6, cc = idx & 63;
        Wt[(size_t)(w * H_ + h0 + hh) * C_ + c0 + cc] = f2bf(tile[cc][hh]);
    }
}

// ---------------------------------------------------------------------------
// Kernel 2: fused QKV GEMM — ROUND-0 tiling (64 rows x 192 cols, proven 43us;
// the 32x384 retile regressed: halved per-wave MFMA density, doubled Wt/L2
// stream). One change vs round-0: 2-deep x prefetch via manual 2x unroll
// (static register names), giving the HBM/L3 load ~2 barriers of slack.
// V is written t-PERMUTED within each 32-block (consumed by k_attn PV order).
// ---------------------------------------------------------------------------
__global__ __launch_bounds__(256, 3) void k_qkv(const float* __restrict__ x,
                                                const unsigned short* __restrict__ Wt,
                                                unsigned short* __restrict__ Qb,
                                                unsigned short* __restrict__ Kb,
                                                unsigned short* __restrict__ Vt) {
    __shared__ unsigned short a_lds[2][64 * 72];  // 2 x 9216 B
    int tid = threadIdx.x;
    int wv = tid >> 6, lane = tid & 63, quad = lane >> 4, lo = lane & 15;
    int r0 = blockIdx.x * 64;
    int cb = blockIdx.y;
    int nt0 = wv * 3;

    f32x4 acc[3][4];
#pragma unroll
    for (int i = 0; i < 3; i++)
#pragma unroll
        for (int j = 0; j < 4; j++) acc[i][j] = (f32x4){0.f, 0.f, 0.f, 0.f};

    const int row_s = tid >> 2;
    const int seg_s = (tid & 3) * 16;
    size_t xbase = (size_t)(r0 + row_s) * C_ + seg_s;

    const unsigned short* wp[3];
#pragma unroll
    for (int nt = 0; nt < 3; nt++)
        wp[nt] = Wt + (size_t)(cb * 192 + (nt0 + nt) * 16 + lo) * C_ + quad * 8;

    auto pack_store = [&](unsigned short* buf, const float4 (&f)[4]) {
        uint4 u0, u1;
        u0.x = (unsigned)f2bf(f[0].x) | ((unsigned)f2bf(f[0].y) << 16);
        u0.y = (unsigned)f2bf(f[0].z) | ((unsigned)f2bf(f[0].w) << 16);
        u0.z = (unsigned)f2bf(f[1].x) | ((unsigned)f2bf(f[1].y) << 16);
        u0.w = (unsigned)f2bf(f[1].z) | ((unsigned)f2bf(f[1].w) << 16);
        u1.x = (unsigned)f2bf(f[2].x) | ((unsigned)f2bf(f[2].y) << 16);
        u1.y = (unsigned)f2bf(f[2].z) | ((unsigned)f2bf(f[2].w) << 16);
        u1.z = (unsigned)f2bf(f[3].x) | ((unsigned)f2bf(f[3].y) << 16);
        u1.w = (unsigned)f2bf(f[3].z) | ((unsigned)f2bf(f[3].w) << 16);
        *(uint4*)&buf[row_s * 72 + seg_s] = u0;
        *(uint4*)&buf[row_s * 72 + seg_s + 8] = u1;
    };
    auto load_x = [&](float4 (&f)[4], int kc) {
        const float* xp = x + xbase + kc * 64;
#pragma unroll
        for (int j = 0; j < 4; j++) f[j] = *(const float4*)(xp + j * 4);
    };
    auto compute = [&](const unsigned short* buf, int kc) {
        s16x8 b[3][2];
#pragma unroll
        for (int nt = 0; nt < 3; nt++)
#pragma unroll
            for (int kh = 0; kh < 2; kh++)
                b[nt][kh] = *(const s16x8*)(wp[nt] + kc * 64 + kh * 32);
        s16x8 af[4][2];
#pragma unroll
        for (int mt = 0; mt < 4; mt++)
#pragma unroll
            for (int kh = 0; kh < 2; kh++)
                af[mt][kh] = *(const s16x8*)&buf[(mt * 16 + lo) * 72 + kh * 32 + quad * 8];
#pragma unroll
        for (int nt = 0; nt < 3; nt++)
#pragma unroll
            for (int kh = 0; kh < 2; kh++)
#pragma unroll
                for (int mt = 0; mt < 4; mt++)
                    acc[nt][mt] = __builtin_amdgcn_mfma_f32_16x16x32_bf16(
                        af[mt][kh], b[nt][kh], acc[nt][mt], 0, 0, 0);
    };

    float4 x0[4], x1[4];
    load_x(x0, 0);
    load_x(x1, 1);
    pack_store(a_lds[0], x0);
    __syncthreads();

    for (int kc2 = 0; kc2 < 8; kc2++) {
        int kc = kc2 * 2;
        if (kc + 2 < 16) load_x(x0, kc + 2);   // 2-deep prefetch
        compute(a_lds[0], kc);
        pack_store(a_lds[1], x1);              // x1 issued ~2 barriers ago
        __syncthreads();
        if (kc + 3 < 16) load_x(x1, kc + 3);
        compute(a_lds[1], kc + 1);
        if (kc + 2 < 16) pack_store(a_lds[0], x0);
        __syncthreads();
    }

    // Epilogue. C-layout: row = mt*16 + quad*4 + r, col = cb*192 + (nt0+nt)*16 + lo
#pragma unroll
    for (int nt = 0; nt < 3; nt++) {
        int col = cb * 192 + (nt0 + nt) * 16 + lo;
        int w = col >> 7, h = col & 127;
#pragma unroll
        for (int mt = 0; mt < 4; mt++) {
            int mrow = r0 + mt * 16 + quad * 4;
            if (w == 2) {
                int b = mrow >> 12, t0 = mrow & 4095;
                // permuted t within 32-block (see k_attn PV fragment order)
                int tp = (t0 & ~31) + (((t0 & 15) >> 2) << 3) + (((t0 >> 4) & 1) << 2);
                uint2 pk;
                pk.x = (unsigned)f2bf(acc[nt][mt][0]) | ((unsigned)f2bf(acc[nt][mt][1]) << 16);
                pk.y = (unsigned)f2bf(acc[nt][mt][2]) | ((unsigned)f2bf(acc[nt][mt][3]) << 16);
                *(uint2*)(Vt + (size_t)(b * H_ + h) * T_ + tp) = pk;
            } else if (w == 1) {
                unsigned short* dst = Qb + (size_t)mrow * H_ + h;
#pragma unroll
                for (int r = 0; r < 4; r++)
                    dst[(size_t)r * H_] = f2bf(acc[nt][mt][r] * QSC);
            } else {
                unsigned short* dst = Kb + (size_t)mrow * H_ + h;
#pragma unroll
                for (int r = 0; r < 4; r++)
                    dst[(size_t)r * H_] = f2bf(acc[nt][mt][r]);
            }
        }
    }
}

// ---------------------------------------------------------------------------
// Kernel 3: causal flash attention, S^T formulation.
//  - EQUAL-WORK chunking (<=CH key-tiles per block); grid 4*NCH blocks, ALL
//    co-resident at 4 blocks/CU -> flat occupancy, no imbalance tail.
//  - __launch_bounds__(256,4): PIN VGPR <= 128 so 4-block residency is
//    guaranteed (round-1 only declared 3; residency may have dropped to 2).
//  - T13 defer-max (THR=8): cross-lane max + O-rescale only when triggered.
//  - T5 s_setprio(1) around both MFMA clusters.
//  - causal mask hoisted behind wave-uniform (t == qt).
// CH == 0: direct (no workspace) fallback, full row range per block.
// ---------------------------------------------------------------------------
#define LOAD_KV(kv0)                                                            \
    do {                                                                        \
        const uint4* kg = (const uint4*)(Kb + (size_t)(batch * T_ + (kv0) + srow_k) * H_); \
        pk0 = kg[sseg_k + 0]; pk1 = kg[sseg_k + 1];                             \
        pk2 = kg[sseg_k + 2]; pk3 = kg[sseg_k + 3];                             \
        const uint4* vg = (const uint4*)(Vt + (size_t)(batch * H_ + srow_v) * T_ + (kv0)); \
        pv0 = vg[sseg_v + 0]; pv1 = vg[sseg_v + 1];                             \
        pv2 = vg[sseg_v + 2]; pv3 = vg[sseg_v + 3];                             \
    } while (0)

template <int CH>
__global__ __launch_bounds__(256, 4) void k_attn(const unsigned short* __restrict__ Qb,
                                                 const unsigned short* __restrict__ Kb,
                                                 const unsigned short* __restrict__ Vt,
                                                 float* __restrict__ Opart,
                                                 float* __restrict__ Mpart,
                                                 float* __restrict__ Lpart,
                                                 float* __restrict__ out) {
    __shared__ uint4 kbuf[64 * 16];   // 16 KB
    __shared__ uint4 vbuf[128 * 8];   // 16 KB (t-permuted V^T rows)

    int tid = threadIdx.x;
    int wv = tid >> 6, lane = tid & 63, quad = lane >> 4, lo = lane & 15;

    int id = blockIdx.x;
    int qt, batch, tbeg, tend, slot = 0;
    if constexpr (CH > 0) {
        slot = id >> 2; batch = id & 3;       // slot ascending <=> qt descending
        int s = slot, q = 63;
        for (;;) { int nc = (q + CH) / CH; if (s < nc) break; s -= nc; --q; }
        qt = q;
        tbeg = s * CH;
        tend = min(tbeg + CH, qt + 1);
    } else {
        qt = 63 - (id >> 2); batch = id & 3;
        tbeg = 0; tend = qt + 1;
    }
    int m0 = qt * 64 + wv * 16;
    int query = m0 + lo;

    s16x8 qf[4];
    size_t qrow = (size_t)(batch * T_ + m0 + lo) * H_;
#pragma unroll
    for (int ks = 0; ks < 4; ks++)
        qf[ks] = *(const s16x8*)(Qb + qrow + ks * 32 + quad * 8);

    f32x4 acc_o[8];   // O[query=lo][d = o*16 + quad*4 + r]
#pragma unroll
    for (int o = 0; o < 8; o++) acc_o[o] = (f32x4){0.f, 0.f, 0.f, 0.f};
    float m_i = -INFINITY, l_i = 0.f;   // l_i: per-lane PARTIAL (quad slice)

    const int srow_k = tid >> 2, sseg_k = (tid & 3) * 4;
    const int srow_v = tid >> 1, sseg_v = (tid & 1) * 4;

    uint4 pk0, pk1, pk2, pk3, pv0, pv1, pv2, pv3;
    LOAD_KV(tbeg * 64);

    for (int t = tbeg; t < tend; ++t) {
        int kv0 = t * 64;
        kbuf[srow_k * 16 + ((sseg_k + 0) ^ (srow_k & 15))] = pk0;
        kbuf[srow_k * 16 + ((sseg_k + 1) ^ (srow_k & 15))] = pk1;
        kbuf[srow_k * 16 + ((sseg_k + 2) ^ (srow_k & 15))] = pk2;
        kbuf[srow_k * 16 + ((sseg_k + 3) ^ (srow_k & 15))] = pk3;
        vbuf[srow_v * 8 + ((sseg_v + 0) ^ (srow_v & 7))] = pv0;
        vbuf[srow_v * 8 + ((sseg_v + 1) ^ (srow_v & 7))] = pv1;
        vbuf[srow_v * 8 + ((sseg_v + 2) ^ (srow_v & 7))] = pv2;
        vbuf[srow_v * 8 + ((sseg_v + 3) ^ (srow_v & 7))] = pv3;
        __syncthreads();
        if (t + 1 < tend) LOAD_KV((t + 1) * 64);

        // S^T = K Q^T: lane holds S[query=lo][key = kv0 + nt*16 + quad*4 + r]
        f32x4 s_acc[4];
#pragma unroll
        for (int nt = 0; nt < 4; nt++) s_acc[nt] = (f32x4){0.f, 0.f, 0.f, 0.f};
        __builtin_amdgcn_s_setprio(1);
#pragma unroll
        for (int ks = 0; ks < 4; ks++) {
#pragma unroll
            for (int nt = 0; nt < 4; nt++) {
                s16x8 kf = as_frag(kbuf[(nt * 16 + lo) * 16 + ((ks * 4 + quad) ^ lo)]);
                s_acc[nt] = __builtin_amdgcn_mfma_f32_16x16x32_bf16(kf, qf[ks], s_acc[nt], 0, 0, 0);
            }
        }
        __builtin_amdgcn_s_setprio(0);

        float p[4][4];
#pragma unroll
        for (int nt = 0; nt < 4; nt++)
#pragma unroll
            for (int r = 0; r < 4; r++) p[nt][r] = s_acc[nt][r];
        if (t == qt) {  // wave-uniform: only the diagonal tile masks
#pragma unroll
            for (int nt = 0; nt < 4; nt++)
#pragma unroll
                for (int r = 0; r < 4; r++)
                    if (kv0 + nt * 16 + quad * 4 + r > query) p[nt][r] = -INFINITY;
        }

        // per-lane max only; cross-lane work deferred (T13, THR=8)
        float mx = p[0][0];
#pragma unroll
        for (int nt = 0; nt < 4; nt++)
#pragma unroll
            for (int r = 0; r < 4; r++) mx = fmaxf(mx, p[nt][r]);
        if (__any(mx > m_i + 8.0f)) {
            float rm = fmaxf(mx, __shfl_xor(mx, 16));
            rm = fmaxf(rm, __shfl_xor(rm, 32));
            float mnew = fmaxf(m_i, rm);
            float alpha = exp2f(m_i - mnew);
            l_i *= alpha;
            m_i = mnew;
#pragma unroll
            for (int o = 0; o < 8; o++)
#pragma unroll
                for (int r = 0; r < 4; r++) acc_o[o][r] *= alpha;
        }
        float rs = 0.f;
#pragma unroll
        for (int nt = 0; nt < 4; nt++)
#pragma unroll
            for (int r = 0; r < 4; r++) {
                float pv = exp2f(p[nt][r] - m_i);   // bounded by 2^8
                p[nt][r] = pv;
                rs += pv;
            }
        l_i += rs;   // per-lane partial; summed across quads after loop

        // pack P straight into B-fragments (truncation; P in [0, 256])
        s16x8 pf[2];
#pragma unroll
        for (int kt = 0; kt < 2; kt++) {
            uint4 u;
            u.x = (__float_as_uint(p[2 * kt][0]) >> 16) | ((__float_as_uint(p[2 * kt][1]) >> 16) << 16);
            u.y = (__float_as_uint(p[2 * kt][2]) >> 16) | ((__float_as_uint(p[2 * kt][3]) >> 16) << 16);
            u.z = (__float_as_uint(p[2 * kt + 1][0]) >> 16) | ((__float_as_uint(p[2 * kt + 1][1]) >> 16) << 16);
            u.w = (__float_as_uint(p[2 * kt + 1][2]) >> 16) | ((__float_as_uint(p[2 * kt + 1][3]) >> 16) << 16);
            pf[kt] = as_frag(u);
        }

        // O^T += V^T P^T  (A = vf from permuted vbuf, B = pf)
        __builtin_amdgcn_s_setprio(1);
#pragma unroll
        for (int kt = 0; kt < 2; kt++)
#pragma unroll
            for (int o = 0; o < 8; o++) {
                int vrow = o * 16 + lo;
                s16x8 vf = as_frag(vbuf[vrow * 8 + ((kt * 4 + quad) ^ (vrow & 7))]);
                acc_o[o] = __builtin_amdgcn_mfma_f32_16x16x32_bf16(vf, pf[kt], acc_o[o], 0, 0, 0);
            }
        __builtin_amdgcn_s_setprio(0);
        __syncthreads();
    }

    l_i += __shfl_xor(l_i, 16);
    l_i += __shfl_xor(l_i, 32);

    if constexpr (CH > 0) {
        constexpr int NCH = chunks_total(CH);
        size_t pr = (size_t)(batch * NCH + slot) * 64 + wv * 16 + lo;
        float* Op = Opart + pr * 128;
#pragma unroll
        for (int o = 0; o < 8; o++) {
            float4 v = {acc_o[o][0], acc_o[o][1], acc_o[o][2], acc_o[o][3]};
            *(float4*)(Op + o * 16 + quad * 4) = v;
        }
        if (quad == 0) { Mpart[pr] = m_i; Lpart[pr] = l_i; }
    } else {
        float inv = 1.0f / l_i;
        int rowg = batch * T_ + m0 + lo;
#pragma unroll
        for (int o = 0; o < 8; o++) {
            float4 v = {acc_o[o][0] * inv, acc_o[o][1] * inv,
                        acc_o[o][2] * inv, acc_o[o][3] * inv};
            *(float4*)(out + (size_t)rowg * H_ + o * 16 + quad * 4) = v;
        }
    }
}

// ---------------------------------------------------------------------------
// Kernel 4: combine variable-count partials, online flash-rescale (no arrays
// -> no scratch). Slot base for qt via closed form of S(n) = sum ceil(k/CH).
// ---------------------------------------------------------------------------
template <int CH>
__global__ __launch_bounds__(256) void k_comb(const float* __restrict__ Opart,
                                              const float* __restrict__ Mpart,
                                              const float* __restrict__ Lpart,
                                              float* __restrict__ out) {
    constexpr int NCH = chunks_total(CH);
    int tid = threadIdx.x;
    int row = blockIdx.x * 8 + (tid >> 5);
    int h4 = (tid & 31) * 4;
    int batch = row >> 12, t = row & 4095, qt = t >> 6;
    int n = qt + 1;
    int nc = (qt + CH) / CH;
    int a = n / CH, b = n % CH;
    int S = CH * a * (a + 1) / 2 + b * (a + 1);
    int base = NCH - S;
    float M = -INFINITY, den = 0.f;
    float4 o = {0.f, 0.f, 0.f, 0.f};
    for (int s = 0; s < nc; ++s) {
        size_t pr = (size_t)(batch * NCH + base + s) * 64 + (t & 63);
        float ms = Mpart[pr], ls = Lpart[pr];
        float4 v = *(const float4*)(Opart + pr * 128 + h4);
        float Mn = fmaxf(M, ms);
        float wa = exp2f(M - Mn), wb = exp2f(ms - Mn);
        den = den * wa + ls * wb;
        o.x = o.x * wa + v.x * wb;
        o.y = o.y * wa + v.y * wb;
        o.z = o.z * wa + v.z * wb;
        o.w = o.w * wa + v.w * wb;
        M = Mn;
    }
    float inv = 1.0f / den;
    float4 r = {o.x * inv, o.y * inv, o.z * inv, o.w * inv};
    *(float4*)(out + (size_t)row * H_ + h4) = r;
}

// ---------------------------------------------------------------------------
extern "C" void kernel_launch(void* const* d_in, const int* in_sizes, int n_in,
                              void* d_out, int out_size, void* d_ws, size_t ws_size,
                              hipStream_t stream) {
    const float* x  = (const float*)d_in[0];
    const float* Wk = (const float*)d_in[1];
    const float* Wq = (const float*)d_in[2];
    const float* Wv = (const float*)d_in[3];
    char* ws = (char*)d_ws;
    unsigned short* Wt = (unsigned short*)ws;                 // 768 KB
    unsigned short* Qb = (unsigned short*)(ws + (1u << 20));  // 4 MB
    unsigned short* Kb = (unsigned short*)(ws + (5u << 20));  // 4 MB
    unsigned short* Vt = (unsigned short*)(ws + (9u << 20));  // 4 MB -> end 13 MB
    float* out = (float*)d_out;

    const size_t base = (size_t)13 << 20;
    constexpr int NCH10 = chunks_total(10);  // 238 chunks/batch -> 952 blocks
    constexpr int NCH21 = chunks_total(21);  // 130 chunks/batch (smaller ws)
    auto need_for = [&](int nch) {
        return base + (size_t)4 * nch * 64 * (128 * 4) + 2 * (size_t)4 * nch * 64 * 4;
    };

    k_wt  <<<dim3(16, 2, 3), 256, 0, stream>>>(Wk, Wq, Wv, Wt);
    k_qkv <<<dim3(256, 2), 256, 0, stream>>>(x, Wt, Qb, Kb, Vt);

    if (ws_size >= need_for(NCH10)) {
        float* Op = (float*)(ws + base);
        float* Mp = Op + (size_t)4 * NCH10 * 64 * 128;
        float* Lp = Mp + (size_t)4 * NCH10 * 64;
        k_attn<10><<<4 * NCH10, 256, 0, stream>>>(Qb, Kb, Vt, Op, Mp, Lp, out);
        k_comb<10><<<2048, 256, 0, stream>>>(Op, Mp, Lp, out);
    } else if (ws_size >= need_for(NCH21)) {
        float* Op = (float*)(ws + base);
        float* Mp = Op + (size_t)4 * NCH21 * 64 * 128;
        float* Lp = Mp + (size_t)4 * NCH21 * 64;
        k_attn<21><<<4 * NCH21, 256, 0, stream>>>(Qb, Kb, Vt, Op, Mp, Lp, out);
        k_comb<21><<<2048, 256, 0, stream>>>(Op, Mp, Lp, out);
    } else {
        k_attn<0><<<256, 256, 0, stream>>>(Qb, Kb, Vt, nullptr, nullptr, nullptr, out);
    }
}

// Round 3
// 172.938 us; speedup vs baseline: 1.1019x; 1.0099x over previous
//
#include <hip/hip_runtime.h>
#include <stdint.h>
#include <math.h>

#define B_ 4
#define T_ 4096
#define C_ 1024
#define H_ 128

typedef __attribute__((ext_vector_type(8))) short s16x8;   // 8 bf16 (4 VGPRs)
typedef __attribute__((ext_vector_type(4))) float f32x4;   // MFMA accumulator

__device__ __forceinline__ unsigned short f2bf(float f) {
    union { float f; unsigned u; } v; v.f = f;
    unsigned r = v.u + 0x7fffu + ((v.u >> 16) & 1u);
    return (unsigned short)(r >> 16);
}

__device__ __forceinline__ s16x8 as_frag(uint4 u) {
    union { uint4 u; s16x8 s; } v; v.u = u; return v.s;
}

// number of work-chunks per batch for chunk size CH (64 key-tiles max)
__host__ __device__ constexpr int chunks_total(int CH) {
    int a = 64 / CH, b = 64 % CH;
    return CH * a * (a + 1) / 2 + b * (a + 1);
}

// softmax scale folded into Q at projection time: 1/sqrt(128) * log2(e)
#define QSC (0.0883883476f * 1.4426950408f)

// ---------------------------------------------------------------------------
// Kernel 1: W [1024][128] fp32 -> Wt [3*128][1024] bf16 (transposed, converted)
// ---------------------------------------------------------------------------
__global__ __launch_bounds__(256) void k_wt(const float* __restrict__ Wk,
                                            const float* __restrict__ Wq,
                                            const float* __restrict__ Wv,
                                            unsigned short* __restrict__ Wt) {
    __shared__ float tile[64][65];
    int w = blockIdx.z;  // 0=K, 1=Q, 2=V
    const float* W = (w == 0) ? Wk : (w == 1) ? Wq : Wv;
    int c0 = blockIdx.x * 64, h0 = blockIdx.y * 64;
    int tid = threadIdx.x;
#pragma unroll
    for (int k = 0; k < 16; k++) {
        int idx = tid + k * 256;
        int r = idx >> 6, c = idx & 63;
        tile[r][c] = W[(size_t)(c0 + r) * H_ + h0 + c];
    }
    __syncthreads();
#pragma unroll
    for (int k = 0; k < 16; k++) {
        int idx = tid + k * 256;
        int hh = idx >> 6, cc = idx & 63;
        Wt[(size_t)(w * H_ + h0 + hh) * C_ + c0 + cc] = f2bf(tile[cc][hh]);
    }
}

// ---------------------------------------------------------------------------
// Kernel 2: fused QKV GEMM — round-0 tiling (64 rows x 192 cols, grid (256,2),
// 24 MFMA/kc/wave) + ONE change: 1-deep register B-prefetch. The Wt (B) loads
// were issued inside compute(), i.e. AFTER the barrier and directly feeding
// the MFMAs; the compiler cannot hoist global loads across __syncthreads, so
// every kc paid ~200-400 cyc of L2 latency on the MFMA path. Prefetch kc+1's
// B-frags during kc's compute via manual 2x-unrolled static ping-pong (b0/b1).
// (x prefetch stays 1-deep: the 2-deep variant regressed in round 2.)
// V is written t-PERMUTED within each 32-block (consumed by k_attn PV order).
// ---------------------------------------------------------------------------
__global__ __launch_bounds__(256, 3) void k_qkv(const float* __restrict__ x,
                                                const unsigned short* __restrict__ Wt,
                                                unsigned short* __restrict__ Qb,
                                                unsigned short* __restrict__ Kb,
                                                unsigned short* __restrict__ Vt) {
    __shared__ unsigned short a_lds[2][64 * 72];  // 2 x 9216 B
    int tid = threadIdx.x;
    int wv = tid >> 6, lane = tid & 63, quad = lane >> 4, lo = lane & 15;
    int r0 = blockIdx.x * 64;
    int cb = blockIdx.y;
    int nt0 = wv * 3;

    f32x4 acc[3][4];
#pragma unroll
    for (int i = 0; i < 3; i++)
#pragma unroll
        for (int j = 0; j < 4; j++) acc[i][j] = (f32x4){0.f, 0.f, 0.f, 0.f};

    const int row_s = tid >> 2;
    const int seg_s = (tid & 3) * 16;
    size_t xbase = (size_t)(r0 + row_s) * C_ + seg_s;

    const unsigned short* wp[3];
#pragma unroll
    for (int nt = 0; nt < 3; nt++)
        wp[nt] = Wt + (size_t)(cb * 192 + (nt0 + nt) * 16 + lo) * C_ + quad * 8;

    auto pack_store = [&](unsigned short* buf, const float4 (&f)[4]) {
        uint4 u0, u1;
        u0.x = (unsigned)f2bf(f[0].x) | ((unsigned)f2bf(f[0].y) << 16);
        u0.y = (unsigned)f2bf(f[0].z) | ((unsigned)f2bf(f[0].w) << 16);
        u0.z = (unsigned)f2bf(f[1].x) | ((unsigned)f2bf(f[1].y) << 16);
        u0.w = (unsigned)f2bf(f[1].z) | ((unsigned)f2bf(f[1].w) << 16);
        u1.x = (unsigned)f2bf(f[2].x) | ((unsigned)f2bf(f[2].y) << 16);
        u1.y = (unsigned)f2bf(f[2].z) | ((unsigned)f2bf(f[2].w) << 16);
        u1.z = (unsigned)f2bf(f[3].x) | ((unsigned)f2bf(f[3].y) << 16);
        u1.w = (unsigned)f2bf(f[3].z) | ((unsigned)f2bf(f[3].w) << 16);
        *(uint4*)&buf[row_s * 72 + seg_s] = u0;
        *(uint4*)&buf[row_s * 72 + seg_s + 8] = u1;
    };
    auto load_x = [&](float4 (&f)[4], int kc) {
        const float* xp = x + xbase + kc * 64;
#pragma unroll
        for (int j = 0; j < 4; j++) f[j] = *(const float4*)(xp + j * 4);
    };
    auto load_b = [&](s16x8 (&b)[3][2], int kc) {
#pragma unroll
        for (int nt = 0; nt < 3; nt++)
#pragma unroll
            for (int kh = 0; kh < 2; kh++)
                b[nt][kh] = *(const s16x8*)(wp[nt] + kc * 64 + kh * 32);
    };
    auto compute = [&](const unsigned short* buf, const s16x8 (&b)[3][2]) {
        s16x8 af[4][2];
#pragma unroll
        for (int mt = 0; mt < 4; mt++)
#pragma unroll
            for (int kh = 0; kh < 2; kh++)
                af[mt][kh] = *(const s16x8*)&buf[(mt * 16 + lo) * 72 + kh * 32 + quad * 8];
#pragma unroll
        for (int nt = 0; nt < 3; nt++)
#pragma unroll
            for (int kh = 0; kh < 2; kh++)
#pragma unroll
                for (int mt = 0; mt < 4; mt++)
                    acc[nt][mt] = __builtin_amdgcn_mfma_f32_16x16x32_bf16(
                        af[mt][kh], b[nt][kh], acc[nt][mt], 0, 0, 0);
    };

    s16x8 b0[3][2], b1[3][2];
    float4 xr[4];
    load_x(xr, 0);
    load_b(b0, 0);
    pack_store(a_lds[0], xr);
    __syncthreads();

#pragma unroll 1
    for (int kc2 = 0; kc2 < 8; kc2++) {
        int kc = kc2 * 2;
        // iter A: compute kc (buf 0, b0); prefetch b1 for kc+1, x for kc+1
        load_b(b1, kc + 1);
        load_x(xr, kc + 1);
        compute(a_lds[0], b0);
        pack_store(a_lds[1], xr);
        __syncthreads();
        // iter B: compute kc+1 (buf 1, b1); prefetch b0/x for kc+2
        if (kc + 2 < 16) {
            load_b(b0, kc + 2);
            load_x(xr, kc + 2);
        }
        compute(a_lds[1], b1);
        if (kc + 2 < 16) pack_store(a_lds[0], xr);
        __syncthreads();
    }

    // Epilogue. C-layout: row = mt*16 + quad*4 + r, col = cb*192 + (nt0+nt)*16 + lo
#pragma unroll
    for (int nt = 0; nt < 3; nt++) {
        int col = cb * 192 + (nt0 + nt) * 16 + lo;
        int w = col >> 7, h = col & 127;
#pragma unroll
        for (int mt = 0; mt < 4; mt++) {
            int mrow = r0 + mt * 16 + quad * 4;
            if (w == 2) {
                int b = mrow >> 12, t0 = mrow & 4095;
                // permuted t within 32-block (see k_attn PV fragment order)
                int tp = (t0 & ~31) + (((t0 & 15) >> 2) << 3) + (((t0 >> 4) & 1) << 2);
                uint2 pk;
                pk.x = (unsigned)f2bf(acc[nt][mt][0]) | ((unsigned)f2bf(acc[nt][mt][1]) << 16);
                pk.y = (unsigned)f2bf(acc[nt][mt][2]) | ((unsigned)f2bf(acc[nt][mt][3]) << 16);
                *(uint2*)(Vt + (size_t)(b * H_ + h) * T_ + tp) = pk;
            } else if (w == 1) {
                unsigned short* dst = Qb + (size_t)mrow * H_ + h;
#pragma unroll
                for (int r = 0; r < 4; r++)
                    dst[(size_t)r * H_] = f2bf(acc[nt][mt][r] * QSC);
            } else {
                unsigned short* dst = Kb + (size_t)mrow * H_ + h;
#pragma unroll
                for (int r = 0; r < 4; r++)
                    dst[(size_t)r * H_] = f2bf(acc[nt][mt][r]);
            }
        }
    }
}

// ---------------------------------------------------------------------------
// Kernel 3: causal flash attention, S^T formulation. (unchanged from round 2)
//  - EQUAL-WORK chunking (<=CH key-tiles per block); all blocks co-resident.
//  - __launch_bounds__(256,4): pin VGPR <= 128 for 4-block residency.
//  - T13 defer-max (THR=8); T5 setprio around MFMA clusters; hoisted mask.
// CH == 0: direct (no workspace) fallback, full row range per block.
// ---------------------------------------------------------------------------
#define LOAD_KV(kv0)                                                            \
    do {                                                                        \
        const uint4* kg = (const uint4*)(Kb + (size_t)(batch * T_ + (kv0) + srow_k) * H_); \
        pk0 = kg[sseg_k + 0]; pk1 = kg[sseg_k + 1];                             \
        pk2 = kg[sseg_k + 2]; pk3 = kg[sseg_k + 3];                             \
        const uint4* vg = (const uint4*)(Vt + (size_t)(batch * H_ + srow_v) * T_ + (kv0)); \
        pv0 = vg[sseg_v + 0]; pv1 = vg[sseg_v + 1];                             \
        pv2 = vg[sseg_v + 2]; pv3 = vg[sseg_v + 3];                             \
    } while (0)

template <int CH>
__global__ __launch_bounds__(256, 4) void k_attn(const unsigned short* __restrict__ Qb,
                                                 const unsigned short* __restrict__ Kb,
                                                 const unsigned short* __restrict__ Vt,
                                                 float* __restrict__ Opart,
                                                 float* __restrict__ Mpart,
                                                 float* __restrict__ Lpart,
                                                 float* __restrict__ out) {
    __shared__ uint4 kbuf[64 * 16];   // 16 KB
    __shared__ uint4 vbuf[128 * 8];   // 16 KB (t-permuted V^T rows)

    int tid = threadIdx.x;
    int wv = tid >> 6, lane = tid & 63, quad = lane >> 4, lo = lane & 15;

    int id = blockIdx.x;
    int qt, batch, tbeg, tend, slot = 0;
    if constexpr (CH > 0) {
        slot = id >> 2; batch = id & 3;       // slot ascending <=> qt descending
        int s = slot, q = 63;
        for (;;) { int nc = (q + CH) / CH; if (s < nc) break; s -= nc; --q; }
        qt = q;
        tbeg = s * CH;
        tend = min(tbeg + CH, qt + 1);
    } else {
        qt = 63 - (id >> 2); batch = id & 3;
        tbeg = 0; tend = qt + 1;
    }
    int m0 = qt * 64 + wv * 16;
    int query = m0 + lo;

    s16x8 qf[4];
    size_t qrow = (size_t)(batch * T_ + m0 + lo) * H_;
#pragma unroll
    for (int ks = 0; ks < 4; ks++)
        qf[ks] = *(const s16x8*)(Qb + qrow + ks * 32 + quad * 8);

    f32x4 acc_o[8];   // O[query=lo][d = o*16 + quad*4 + r]
#pragma unroll
    for (int o = 0; o < 8; o++) acc_o[o] = (f32x4){0.f, 0.f, 0.f, 0.f};
    float m_i = -INFINITY, l_i = 0.f;   // l_i: per-lane PARTIAL (quad slice)

    const int srow_k = tid >> 2, sseg_k = (tid & 3) * 4;
    const int srow_v = tid >> 1, sseg_v = (tid & 1) * 4;

    uint4 pk0, pk1, pk2, pk3, pv0, pv1, pv2, pv3;
    LOAD_KV(tbeg * 64);

    for (int t = tbeg; t < tend; ++t) {
        int kv0 = t * 64;
        kbuf[srow_k * 16 + ((sseg_k + 0) ^ (srow_k & 15))] = pk0;
        kbuf[srow_k * 16 + ((sseg_k + 1) ^ (srow_k & 15))] = pk1;
        kbuf[srow_k * 16 + ((sseg_k + 2) ^ (srow_k & 15))] = pk2;
        kbuf[srow_k * 16 + ((sseg_k + 3) ^ (srow_k & 15))] = pk3;
        vbuf[srow_v * 8 + ((sseg_v + 0) ^ (srow_v & 7))] = pv0;
        vbuf[srow_v * 8 + ((sseg_v + 1) ^ (srow_v & 7))] = pv1;
        vbuf[srow_v * 8 + ((sseg_v + 2) ^ (srow_v & 7))] = pv2;
        vbuf[srow_v * 8 + ((sseg_v + 3) ^ (srow_v & 7))] = pv3;
        __syncthreads();
        if (t + 1 < tend) LOAD_KV((t + 1) * 64);

        // S^T = K Q^T: lane holds S[query=lo][key = kv0 + nt*16 + quad*4 + r]
        f32x4 s_acc[4];
#pragma unroll
        for (int nt = 0; nt < 4; nt++) s_acc[nt] = (f32x4){0.f, 0.f, 0.f, 0.f};
        __builtin_amdgcn_s_setprio(1);
#pragma unroll
        for (int ks = 0; ks < 4; ks++) {
#pragma unroll
            for (int nt = 0; nt < 4; nt++) {
                s16x8 kf = as_frag(kbuf[(nt * 16 + lo) * 16 + ((ks * 4 + quad) ^ lo)]);
                s_acc[nt] = __builtin_amdgcn_mfma_f32_16x16x32_bf16(kf, qf[ks], s_acc[nt], 0, 0, 0);
            }
        }
        __builtin_amdgcn_s_setprio(0);

        float p[4][4];
#pragma unroll
        for (int nt = 0; nt < 4; nt++)
#pragma unroll
            for (int r = 0; r < 4; r++) p[nt][r] = s_acc[nt][r];
        if (t == qt) {  // wave-uniform: only the diagonal tile masks
#pragma unroll
            for (int nt = 0; nt < 4; nt++)
#pragma unroll
                for (int r = 0; r < 4; r++)
                    if (kv0 + nt * 16 + quad * 4 + r > query) p[nt][r] = -INFINITY;
        }

        // per-lane max only; cross-lane work deferred (T13, THR=8)
        float mx = p[0][0];
#pragma unroll
        for (int nt = 0; nt < 4; nt++)
#pragma unroll
            for (int r = 0; r < 4; r++) mx = fmaxf(mx, p[nt][r]);
        if (__any(mx > m_i + 8.0f)) {
            float rm = fmaxf(mx, __shfl_xor(mx, 16));
            rm = fmaxf(rm, __shfl_xor(rm, 32));
            float mnew = fmaxf(m_i, rm);
            float alpha = exp2f(m_i - mnew);
            l_i *= alpha;
            m_i = mnew;
#pragma unroll
            for (int o = 0; o < 8; o++)
#pragma unroll
                for (int r = 0; r < 4; r++) acc_o[o][r] *= alpha;
        }
        float rs = 0.f;
#pragma unroll
        for (int nt = 0; nt < 4; nt++)
#pragma unroll
            for (int r = 0; r < 4; r++) {
                float pv = exp2f(p[nt][r] - m_i);   // bounded by 2^8
                p[nt][r] = pv;
                rs += pv;
            }
        l_i += rs;   // per-lane partial; summed across quads after loop

        // pack P straight into B-fragments (truncation; P in [0, 256])
        s16x8 pf[2];
#pragma unroll
        for (int kt = 0; kt < 2; kt++) {
            uint4 u;
            u.x = (__float_as_uint(p[2 * kt][0]) >> 16) | ((__float_as_uint(p[2 * kt][1]) >> 16) << 16);
            u.y = (__float_as_uint(p[2 * kt][2]) >> 16) | ((__float_as_uint(p[2 * kt][3]) >> 16) << 16);
            u.z = (__float_as_uint(p[2 * kt + 1][0]) >> 16) | ((__float_as_uint(p[2 * kt + 1][1]) >> 16) << 16);
            u.w = (__float_as_uint(p[2 * kt + 1][2]) >> 16) | ((__float_as_uint(p[2 * kt + 1][3]) >> 16) << 16);
            pf[kt] = as_frag(u);
        }

        // O^T += V^T P^T  (A = vf from permuted vbuf, B = pf)
        __builtin_amdgcn_s_setprio(1);
#pragma unroll
        for (int kt = 0; kt < 2; kt++)
#pragma unroll
            for (int o = 0; o < 8; o++) {
                int vrow = o * 16 + lo;
                s16x8 vf = as_frag(vbuf[vrow * 8 + ((kt * 4 + quad) ^ (vrow & 7))]);
                acc_o[o] = __builtin_amdgcn_mfma_f32_16x16x32_bf16(vf, pf[kt], acc_o[o], 0, 0, 0);
            }
        __builtin_amdgcn_s_setprio(0);
        __syncthreads();
    }

    l_i += __shfl_xor(l_i, 16);
    l_i += __shfl_xor(l_i, 32);

    if constexpr (CH > 0) {
        constexpr int NCH = chunks_total(CH);
        size_t pr = (size_t)(batch * NCH + slot) * 64 + wv * 16 + lo;
        float* Op = Opart + pr * 128;
#pragma unroll
        for (int o = 0; o < 8; o++) {
            float4 v = {acc_o[o][0], acc_o[o][1], acc_o[o][2], acc_o[o][3]};
            *(float4*)(Op + o * 16 + quad * 4) = v;
        }
        if (quad == 0) { Mpart[pr] = m_i; Lpart[pr] = l_i; }
    } else {
        float inv = 1.0f / l_i;
        int rowg = batch * T_ + m0 + lo;
#pragma unroll
        for (int o = 0; o < 8; o++) {
            float4 v = {acc_o[o][0] * inv, acc_o[o][1] * inv,
                        acc_o[o][2] * inv, acc_o[o][3] * inv};
            *(float4*)(out + (size_t)rowg * H_ + o * 16 + quad * 4) = v;
        }
    }
}

// ---------------------------------------------------------------------------
// Kernel 4: combine variable-count partials, online flash-rescale (no arrays
// -> no scratch). Slot base for qt via closed form of S(n) = sum ceil(k/CH).
// ---------------------------------------------------------------------------
template <int CH>
__global__ __launch_bounds__(256) void k_comb(const float* __restrict__ Opart,
                                              const float* __restrict__ Mpart,
                                              const float* __restrict__ Lpart,
                                              float* __restrict__ out) {
    constexpr int NCH = chunks_total(CH);
    int tid = threadIdx.x;
    int row = blockIdx.x * 8 + (tid >> 5);
    int h4 = (tid & 31) * 4;
    int batch = row >> 12, t = row & 4095, qt = t >> 6;
    int n = qt + 1;
    int nc = (qt + CH) / CH;
    int a = n / CH, b = n % CH;
    int S = CH * a * (a + 1) / 2 + b * (a + 1);
    int base = NCH - S;
    float M = -INFINITY, den = 0.f;
    float4 o = {0.f, 0.f, 0.f, 0.f};
    for (int s = 0; s < nc; ++s) {
        size_t pr = (size_t)(batch * NCH + base + s) * 64 + (t & 63);
        float ms = Mpart[pr], ls = Lpart[pr];
        float4 v = *(const float4*)(Opart + pr * 128 + h4);
        float Mn = fmaxf(M, ms);
        float wa = exp2f(M - Mn), wb = exp2f(ms - Mn);
        den = den * wa + ls * wb;
        o.x = o.x * wa + v.x * wb;
        o.y = o.y * wa + v.y * wb;
        o.z = o.z * wa + v.z * wb;
        o.w = o.w * wa + v.w * wb;
        M = Mn;
    }
    float inv = 1.0f / den;
    float4 r = {o.x * inv, o.y * inv, o.z * inv, o.w * inv};
    *(float4*)(out + (size_t)row * H_ + h4) = r;
}

// ---------------------------------------------------------------------------
extern "C" void kernel_launch(void* const* d_in, const int* in_sizes, int n_in,
                              void* d_out, int out_size, void* d_ws, size_t ws_size,
                              hipStream_t stream) {
    const float* x  = (const float*)d_in[0];
    const float* Wk = (const float*)d_in[1];
    const float* Wq = (const float*)d_in[2];
    const float* Wv = (const float*)d_in[3];
    char* ws = (char*)d_ws;
    unsigned short* Wt = (unsigned short*)ws;                 // 768 KB
    unsigned short* Qb = (unsigned short*)(ws + (1u << 20));  // 4 MB
    unsigned short* Kb = (unsigned short*)(ws + (5u << 20));  // 4 MB
    unsigned short* Vt = (unsigned short*)(ws + (9u << 20));  // 4 MB -> end 13 MB
    float* out = (float*)d_out;

    const size_t base = (size_t)13 << 20;
    constexpr int NCH10 = chunks_total(10);  // 238 chunks/batch -> 952 blocks
    constexpr int NCH21 = chunks_total(21);  // 130 chunks/batch (smaller ws)
    auto need_for = [&](int nch) {
        return base + (size_t)4 * nch * 64 * (128 * 4) + 2 * (size_t)4 * nch * 64 * 4;
    };

    k_wt  <<<dim3(16, 2, 3), 256, 0, stream>>>(Wk, Wq, Wv, Wt);
    k_qkv <<<dim3(256, 2), 256, 0, stream>>>(x, Wt, Qb, Kb, Vt);

    if (ws_size >= need_for(NCH10)) {
        float* Op = (float*)(ws + base);
        float* Mp = Op + (size_t)4 * NCH10 * 64 * 128;
        float* Lp = Mp + (size_t)4 * NCH10 * 64;
        k_attn<10><<<4 * NCH10, 256, 0, stream>>>(Qb, Kb, Vt, Op, Mp, Lp, out);
        k_comb<10><<<2048, 256, 0, stream>>>(Op, Mp, Lp, out);
    } else if (ws_size >= need_for(NCH21)) {
        float* Op = (float*)(ws + base);
        float* Mp = Op + (size_t)4 * NCH21 * 64 * 128;
        float* Lp = Mp + (size_t)4 * NCH21 * 64;
        k_attn<21><<<4 * NCH21, 256, 0, stream>>>(Qb, Kb, Vt, Op, Mp, Lp, out);
        k_comb<21><<<2048, 256, 0, stream>>>(Op, Mp, Lp, out);
    } else {
        k_attn<0><<<256, 256, 0, stream>>>(Qb, Kb, Vt, nullptr, nullptr, nullptr, out);
    }
}